// Round 2
// baseline (294.073 us; speedup 1.0000x reference)
//
#include <hip/hip_runtime.h>
#include <hip/hip_bf16.h>

// GraphProp: layered DAG topological propagation.
// N=50000 nodes, L=16 levels, PER=3125 nodes/level, DEG=16 in-edges, D=64 feat dim.
// Edges sorted by dst; node v (v >= PER) owns edges [(v-PER)*16, (v-PER)*16+16).
// feat[v] = max_k(feat[src_k] + intra_delay[src_k]) + delay[v], level order.
//
// Single persistent kernel, one grid barrier per level (release atomicAdd +
// relaxed agent-scope spin + acquire fence; 256 blocks x 256 thr trivially
// co-resident on 256 CUs). msg[v] = feat_final[v] + intra[v] is maintained
// incrementally in d_ws, halving per-edge gather traffic.

#define NN    50000
#define LVL   16
#define PER   3125
#define DEG   16
#define DF    64

#define NBLK  256
#define NTHR  256
#define NWAVES ((NBLK * NTHR) / 64)   // 1024 waves

__device__ __forceinline__ void grid_barrier(unsigned* counter, unsigned target) {
    __syncthreads();                       // compiler drains vmcnt before s_barrier
    if (threadIdx.x == 0) {
        // release: prior block stores (already in L2 after barrier drain) -> device
        __hip_atomic_fetch_add(counter, 1u, __ATOMIC_RELEASE, __HIP_MEMORY_SCOPE_AGENT);
        while (__hip_atomic_load(counter, __ATOMIC_RELAXED, __HIP_MEMORY_SCOPE_AGENT) < target) {
            __builtin_amdgcn_s_sleep(1);
        }
        __builtin_amdgcn_fence(__ATOMIC_ACQUIRE, "agent");   // invalidate stale cache
    }
    __syncthreads();
}

__global__ void __launch_bounds__(NTHR) prop_all(
    const float* __restrict__ feat,
    const float* __restrict__ delay,
    const float* __restrict__ intra,
    const int*  __restrict__ src,
    float* __restrict__ out,
    float* __restrict__ msg,
    unsigned* __restrict__ counter)
{
    const int tid = blockIdx.x * NTHR + threadIdx.x;

    // Phase 0: level-0 init only (everything else is overwritten at its level).
    for (int i = tid; i < PER * DF; i += NBLK * NTHR) {
        const float f = feat[i];
        out[i] = f;
        msg[i] = f + intra[i];
    }

    const int wid = tid >> 6;            // wave id, uniform across the wave
    const int d   = threadIdx.x & 63;    // feature index = lane

    for (int l = 1; l < LVL; ++l) {
        grid_barrier(counter, (unsigned)(l * NBLK));
        for (int idx = wid; idx < PER; idx += NWAVES) {
            const int v = __builtin_amdgcn_readfirstlane(l * PER + idx);
            const int* sp = src + (size_t)(v - PER) * DEG;   // wave-uniform -> s_load
            float m = -INFINITY;
#pragma unroll
            for (int k = 0; k < DEG; ++k) {
                const int s = sp[k];
                m = fmaxf(m, msg[(size_t)s * DF + d]);
            }
            const float o = m + delay[(size_t)v * DF + d];
            out[(size_t)v * DF + d] = o;
            if (l < LVL - 1)                                  // last level: nobody reads msg
                msg[(size_t)v * DF + d] = o + intra[(size_t)v * DF + d];
        }
    }
}

// ---- fallback path (if ws_size too small for msg buffer): round-1 approach ----
__global__ void __launch_bounds__(256) prop_level(
    float* __restrict__ feat, const float* __restrict__ intra,
    const float* __restrict__ delay, const int* __restrict__ src, int level_start)
{
    const int idx = blockIdx.x * 4 + (threadIdx.x >> 6);
    if (idx >= PER) return;
    const int v = level_start + idx;
    const int d = threadIdx.x & 63;
    const long ebase = (long)(v - PER) * DEG;
    float m = -INFINITY;
#pragma unroll
    for (int k = 0; k < DEG; ++k) {
        const int s = src[ebase + k];
        m = fmaxf(m, feat[(long)s * DF + d] + intra[(long)s * DF + d]);
    }
    feat[(long)v * DF + d] = m + delay[(long)v * DF + d];
}

extern "C" void kernel_launch(void* const* d_in, const int* in_sizes, int n_in,
                              void* d_out, int out_size, void* d_ws, size_t ws_size,
                              hipStream_t stream) {
    const float* feat  = (const float*)d_in[0];
    const float* delay = (const float*)d_in[1];
    const float* intra = (const float*)d_in[2];
    const int*   src   = (const int*)d_in[3];
    float* out = (float*)d_out;

    const size_t need = 256 + (size_t)NN * DF * sizeof(float);
    if (ws_size >= need) {
        unsigned* counter = (unsigned*)d_ws;
        float*    msg     = (float*)((char*)d_ws + 256);
        hipMemsetAsync(d_ws, 0, 256, stream);                 // reset barrier counter
        prop_all<<<NBLK, NTHR, 0, stream>>>(feat, delay, intra, src, out, msg, counter);
    } else {
        hipMemcpyAsync(out, feat, (size_t)NN * DF * sizeof(float),
                       hipMemcpyDeviceToDevice, stream);
        const int blocks = (PER + 3) / 4;
        for (int l = 1; l < LVL; ++l)
            prop_level<<<blocks, 256, 0, stream>>>(out, intra, delay, src, l * PER);
    }
}

// Round 3
// 139.530 us; speedup vs baseline: 2.1076x; 2.1076x over previous
//
#include <hip/hip_runtime.h>
#include <hip/hip_bf16.h>

// GraphProp: layered DAG topological propagation.
// N=50000 nodes, L=16 levels, PER=3125 nodes/level, DEG=16 in-edges, D=64 feat dim.
// Edges sorted by dst; node v (v >= PER) owns edges [(v-PER)*16, (v-PER)*16+16).
// feat[v] = max_k(feat[src_k] + intra_delay[src_k]) + delay[v], level order.
//
// Single persistent kernel. Cross-block data (msg) uses agent-scope RELAXED
// atomic ld/st (sc1 -> coherent at LLC, bypasses per-XCD L2) so NO cache
// fences are needed anywhere -- R2 showed agent release/acquire fences cost
// ~200us by flushing L2 every level. Read-only data (src/delay/intra/feat)
// stays in normal cached loads. Barrier = vmcnt(0) drain + relaxed atomicAdd
// + relaxed spin; 256 blocks x 1024 thr = 1 block/CU (co-residency trivial).

#define NN    50000
#define LVL   16
#define PER   3125
#define DEG   16
#define DF    64

#define NBLK  256
#define NTHR  1024

__device__ __forceinline__ float msg_load(const float* p) {
    return __hip_atomic_load(p, __ATOMIC_RELAXED, __HIP_MEMORY_SCOPE_AGENT);
}
__device__ __forceinline__ void msg_store(float* p, float v) {
    __hip_atomic_store(p, v, __ATOMIC_RELAXED, __HIP_MEMORY_SCOPE_AGENT);
}

__global__ void __launch_bounds__(NTHR) prop_all(
    const float* __restrict__ feat,
    const float* __restrict__ delay,
    const float* __restrict__ intra,
    const int*  __restrict__ src,
    float* __restrict__ out,
    float* __restrict__ msg,
    unsigned* __restrict__ counter)
{
    const int tid = blockIdx.x * NTHR + threadIdx.x;

    // Phase 0: level-0 init. out rows for levels>=1 are fully overwritten later.
    for (int i = tid; i < PER * DF; i += NBLK * NTHR) {
        const float f = feat[i];
        out[i] = f;
        msg_store(&msg[i], f + intra[i]);     // sc1 store -> visible at LLC
    }

    const int wid = tid >> 6;            // global wave id: one node per wave
    const int d   = threadIdx.x & 63;    // feature index = lane

    for (int l = 1; l < LVL; ++l) {
        // ---- grid barrier (no cache maintenance) ----
        asm volatile("s_waitcnt vmcnt(0)" ::: "memory");  // our sc1 stores ack'd
        __syncthreads();
        if (threadIdx.x == 0) {
            __hip_atomic_fetch_add(counter, 1u, __ATOMIC_RELAXED,
                                   __HIP_MEMORY_SCOPE_AGENT);
            while (__hip_atomic_load(counter, __ATOMIC_RELAXED,
                                     __HIP_MEMORY_SCOPE_AGENT) < (unsigned)(l * NBLK))
                __builtin_amdgcn_s_sleep(1);
        }
        __syncthreads();
        asm volatile("" ::: "memory");    // keep compiler from hoisting loads

        // ---- level l: one node per wave ----
        if (wid < PER) {
            const int v = l * PER + wid;
            const int* sp = src + (size_t)(v - PER) * DEG;
            float m = -INFINITY;
#pragma unroll
            for (int k = 0; k < DEG; ++k) {
                const int s = __builtin_amdgcn_readfirstlane(sp[k]);
                m = fmaxf(m, msg_load(&msg[(size_t)s * DF + d]));
            }
            const float o = m + delay[(size_t)v * DF + d];
            out[(size_t)v * DF + d] = o;           // normal cached store
            if (l < LVL - 1)                       // last level: nobody reads msg
                msg_store(&msg[(size_t)v * DF + d],
                          o + intra[(size_t)v * DF + d]);
        }
    }
}

// ---- fallback path (ws too small): round-1 multi-kernel approach ----
__global__ void __launch_bounds__(256) prop_level(
    float* __restrict__ feat, const float* __restrict__ intra,
    const float* __restrict__ delay, const int* __restrict__ src, int level_start)
{
    const int idx = blockIdx.x * 4 + (threadIdx.x >> 6);
    if (idx >= PER) return;
    const int v = level_start + idx;
    const int d = threadIdx.x & 63;
    const long ebase = (long)(v - PER) * DEG;
    float m = -INFINITY;
#pragma unroll
    for (int k = 0; k < DEG; ++k) {
        const int s = src[ebase + k];
        m = fmaxf(m, feat[(long)s * DF + d] + intra[(long)s * DF + d]);
    }
    feat[(long)v * DF + d] = m + delay[(long)v * DF + d];
}

extern "C" void kernel_launch(void* const* d_in, const int* in_sizes, int n_in,
                              void* d_out, int out_size, void* d_ws, size_t ws_size,
                              hipStream_t stream) {
    const float* feat  = (const float*)d_in[0];
    const float* delay = (const float*)d_in[1];
    const float* intra = (const float*)d_in[2];
    const int*   src   = (const int*)d_in[3];
    float* out = (float*)d_out;

    const size_t need = 256 + (size_t)NN * DF * sizeof(float);
    if (ws_size >= need) {
        unsigned* counter = (unsigned*)d_ws;
        float*    msg     = (float*)((char*)d_ws + 256);
        hipMemsetAsync(d_ws, 0, 256, stream);     // reset barrier counter each call
        prop_all<<<NBLK, NTHR, 0, stream>>>(feat, delay, intra, src, out, msg, counter);
    } else {
        hipMemcpyAsync(out, feat, (size_t)NN * DF * sizeof(float),
                       hipMemcpyDeviceToDevice, stream);
        const int blocks = (PER + 3) / 4;
        for (int l = 1; l < LVL; ++l)
            prop_level<<<blocks, 256, 0, stream>>>(out, intra, delay, src, l * PER);
    }
}

// Round 4
// 134.860 us; speedup vs baseline: 2.1806x; 1.0346x over previous
//
#include <hip/hip_runtime.h>
#include <hip/hip_bf16.h>

// GraphProp: layered DAG topological propagation.
// N=50000 nodes, L=16 levels, PER=3125 nodes/level, DEG=16 in-edges, D=64 feat dim.
// Edges sorted by dst; node v (v >= PER) owns edges [(v-PER)*16, (v-PER)*16+16).
// feat[v] = max_k(feat[src_k] + intra_delay[src_k]) + delay[v], level order.
//
// Single persistent kernel, one node per wave per level (4096 waves, 256
// blocks x 1024 thr = 1 block/CU, co-residency trivial).
//
// Coherence scheme (no cache-maintenance instructions at all):
//   - msg stores: agent-scope relaxed atomic store (sc1 write-through ->
//     value at LLC before the barrier's vmcnt(0) drain; proven in R3).
//   - msg loads: NORMAL CACHED loads. Safe: each msg line is written once
//     before any read (level order + barrier), and kernel-start acquire
//     invalidates L2, so no L2 can hold a pre-write copy of a line within
//     a replay. Restores intra- and cross-level L2 reuse (R3 bypassed L2
//     on every gather -> 62 MB LLC traffic, 600 GB/s effective).
//   - out stores: normal cached, flushed by kernel-end release.
// Prefetch: next level's src indices + delay + intra issue BEFORE the
// barrier arrival so their latency hides under the barrier wait.

#define NN    50000
#define LVL   16
#define PER   3125
#define DEG   16
#define DF    64

#define NBLK  256
#define NTHR  1024

__device__ __forceinline__ void msg_store(float* p, float v) {
    __hip_atomic_store(p, v, __ATOMIC_RELAXED, __HIP_MEMORY_SCOPE_AGENT);
}

__global__ void __launch_bounds__(NTHR) prop_all(
    const float* __restrict__ feat,
    const float* __restrict__ delay,
    const float* __restrict__ intra,
    const int*  __restrict__ src,
    float* __restrict__ out,
    float* __restrict__ msg,
    unsigned* __restrict__ counter)
{
    const int tid = blockIdx.x * NTHR + threadIdx.x;

    // Phase 0: level-0 init. out rows for levels>=1 are fully overwritten later.
    for (int i = tid; i < PER * DF; i += NBLK * NTHR) {
        const float f = feat[i];
        out[i] = f;
        msg_store(&msg[i], f + intra[i]);     // sc1 -> at LLC before barrier 1
    }

    const int wid    = tid >> 6;              // global wave id: one node per wave
    const int d      = threadIdx.x & 63;      // feature index = lane
    const bool active = (wid < PER);

    int   sidx[DEG];
    float dl = 0.f, it = 0.f;

    // Prefetch for level 1.
    if (active) {
        const int v = PER + wid;
        const int* sp = src + (size_t)(v - PER) * DEG;
#pragma unroll
        for (int k = 0; k < DEG; ++k) sidx[k] = sp[k];
        dl = delay[(size_t)v * DF + d];
        it = intra[(size_t)v * DF + d];
    }

    for (int l = 1; l < LVL; ++l) {
        // ---- grid barrier (no cache maintenance) ----
        asm volatile("s_waitcnt vmcnt(0)" ::: "memory");  // msg stores at LLC
        __syncthreads();
        if (threadIdx.x == 0) {
            __hip_atomic_fetch_add(counter, 1u, __ATOMIC_RELAXED,
                                   __HIP_MEMORY_SCOPE_AGENT);
            while (__hip_atomic_load(counter, __ATOMIC_RELAXED,
                                     __HIP_MEMORY_SCOPE_AGENT) < (unsigned)(l * NBLK))
                __builtin_amdgcn_s_sleep(2);
        }
        __syncthreads();
        asm volatile("" ::: "memory");        // no hoisting loads above barrier

        if (active) {
            // Issue the 16 msg gathers (normal cached loads).
            float g[DEG];
#pragma unroll
            for (int k = 0; k < DEG; ++k)
                g[k] = msg[(size_t)sidx[k] * DF + d];

            const int v = l * PER + wid;
            const float my_dl = dl, my_it = it;

            // Prefetch next level while gathers are in flight.
            if (l + 1 < LVL) {
                const int vn = (l + 1) * PER + wid;
                const int* sp = src + (size_t)(vn - PER) * DEG;
#pragma unroll
                for (int k = 0; k < DEG; ++k) sidx[k] = sp[k];
                dl = delay[(size_t)vn * DF + d];
                it = intra[(size_t)vn * DF + d];
            }

            // Reduce (tree) and write.
            float m = -INFINITY;
#pragma unroll
            for (int k = 0; k < DEG; ++k) m = fmaxf(m, g[k]);

            const float o = m + my_dl;
            out[(size_t)v * DF + d] = o;              // cached, kernel-end flush
            if (l < LVL - 1)                          // last level: nobody reads msg
                msg_store(&msg[(size_t)v * DF + d], o + my_it);
        }
    }
}

// ---- fallback path (ws too small): round-1 multi-kernel approach ----
__global__ void __launch_bounds__(256) prop_level(
    float* __restrict__ feat, const float* __restrict__ intra,
    const float* __restrict__ delay, const int* __restrict__ src, int level_start)
{
    const int idx = blockIdx.x * 4 + (threadIdx.x >> 6);
    if (idx >= PER) return;
    const int v = level_start + idx;
    const int d = threadIdx.x & 63;
    const long ebase = (long)(v - PER) * DEG;
    float m = -INFINITY;
#pragma unroll
    for (int k = 0; k < DEG; ++k) {
        const int s = src[ebase + k];
        m = fmaxf(m, feat[(long)s * DF + d] + intra[(long)s * DF + d]);
    }
    feat[(long)v * DF + d] = m + delay[(long)v * DF + d];
}

extern "C" void kernel_launch(void* const* d_in, const int* in_sizes, int n_in,
                              void* d_out, int out_size, void* d_ws, size_t ws_size,
                              hipStream_t stream) {
    const float* feat  = (const float*)d_in[0];
    const float* delay = (const float*)d_in[1];
    const float* intra = (const float*)d_in[2];
    const int*   src   = (const int*)d_in[3];
    float* out = (float*)d_out;

    const size_t need = 256 + (size_t)NN * DF * sizeof(float);
    if (ws_size >= need) {
        unsigned* counter = (unsigned*)d_ws;
        float*    msg     = (float*)((char*)d_ws + 256);
        hipMemsetAsync(d_ws, 0, 256, stream);     // reset barrier counter each call
        prop_all<<<NBLK, NTHR, 0, stream>>>(feat, delay, intra, src, out, msg, counter);
    } else {
        hipMemcpyAsync(out, feat, (size_t)NN * DF * sizeof(float),
                       hipMemcpyDeviceToDevice, stream);
        const int blocks = (PER + 3) / 4;
        for (int l = 1; l < LVL; ++l)
            prop_level<<<blocks, 256, 0, stream>>>(out, intra, delay, src, l * PER);
    }
}

// Round 5
// 90.001 us; speedup vs baseline: 3.2674x; 1.4984x over previous
//
#include <hip/hip_runtime.h>
#include <hip/hip_bf16.h>

// GraphProp: layered DAG topological propagation.
// N=50000, L=16 levels, PER=3125/level, DEG=16 in-edges, D=64 feat dim.
// Edges sorted by dst; node v (v>=PER) owns edges [(v-PER)*16, (v-PER)*16+16).
// feat[v] = max_k(feat[src_k] + intra_delay[src_k]) + delay[v], level order.
//
// Persistent kernel, one node per wave per level. 256 blocks x 1024 thr =
// 1 block/CU (co-residency guaranteed).
//
// Coherence (R3/R4-proven, no cache maintenance): msg writes are agent-scope
// relaxed atomic stores (sc1 write-through -> at LLC before barrier arrive);
// msg reads are normal cached loads (no line is ever read before written
// within a call, kernel-start acquire invalidates L2 across replays).
//
// R5 barrier redesign (R3==R4 showed ~7us/level is barrier cost, not gathers):
//  - arrive counter and release flag on separate lines: spinners poll the
//    release word (single writer, read-only sharing) instead of the RMW line.
//  - raw asm s_barrier (no compiler vmcnt(0) drain) so prefetched gathers
//    stay in flight ACROSS the barrier.
//  - DAG fact: level-l sources are uniform over [0,l*PER) -> only ~16/l are
//    in level l-1. Sources with s < (l-1)*PER are final+visible one barrier
//    early -> gather them BEFORE arriving; post-barrier critical path is
//    ~16/l fresh gathers + fmax tree + stores.

#define NN    50000
#define LVL   16
#define PER   3125
#define DEG   16
#define DF    64

#define NBLK  256
#define NTHR  1024

__device__ __forceinline__ void msg_store(float* p, float v) {
    __hip_atomic_store(p, v, __ATOMIC_RELAXED, __HIP_MEMORY_SCOPE_AGENT);
}

__global__ void __launch_bounds__(NTHR) prop_all(
    const float* __restrict__ feat,
    const float* __restrict__ delay,
    const float* __restrict__ intra,
    const int*  __restrict__ src,
    float* __restrict__ out,
    float* __restrict__ msg,
    unsigned* __restrict__ counter,    // arrive line
    unsigned* __restrict__ release)    // release line (separate 128B)
{
    const int tid = blockIdx.x * NTHR + threadIdx.x;
    const int wid = tid >> 6;              // one node per wave per level
    const int d   = threadIdx.x & 63;     // feature index = lane
    const bool active = (wid < PER);

    // Phase 0: level-0 init (out rows for levels>=1 are overwritten later).
    for (int i = tid; i < PER * DF; i += NBLK * NTHR) {
        const float f = feat[i];
        out[i] = f;
        msg_store(&msg[i], f + intra[i]);
    }

    int   sidx[DEG];
    float g[DEG];
    float dl = 0.f, it = 0.f;
#pragma unroll
    for (int k = 0; k < DEG; ++k) g[k] = -INFINITY;

    // Prefetch level-1 metadata (all level-1 sources are fresh: no gathers yet).
    if (active) {
        const int vn = PER + wid;
        const int4* sp4 = (const int4*)(src + (size_t)(vn - PER) * DEG);
#pragma unroll
        for (int q = 0; q < 4; ++q) {
            const int4 t = sp4[q];
            sidx[q*4+0] = __builtin_amdgcn_readfirstlane(t.x);
            sidx[q*4+1] = __builtin_amdgcn_readfirstlane(t.y);
            sidx[q*4+2] = __builtin_amdgcn_readfirstlane(t.z);
            sidx[q*4+3] = __builtin_amdgcn_readfirstlane(t.w);
        }
        dl = delay[(size_t)vn * DF + d];
        it = intra[(size_t)vn * DF + d];
    }

    // Drain init msg stores (must be at LLC before arriving at barrier 1).
    asm volatile("s_waitcnt vmcnt(0)" ::: "memory");

    for (int l = 1; l < LVL; ++l) {
        // ---- grid barrier l (arrive/release split, no gather drain) ----
        asm volatile("s_barrier" ::: "memory");    // intra-block arrive
        if (threadIdx.x == 0) {
            __hip_atomic_fetch_add(counter, 1u, __ATOMIC_RELAXED,
                                   __HIP_MEMORY_SCOPE_AGENT);
            if (blockIdx.x == 0) {
                while (__hip_atomic_load(counter, __ATOMIC_RELAXED,
                                         __HIP_MEMORY_SCOPE_AGENT)
                       < (unsigned)(l * NBLK))
                    __builtin_amdgcn_s_sleep(1);
                __hip_atomic_store(release, (unsigned)l, __ATOMIC_RELAXED,
                                   __HIP_MEMORY_SCOPE_AGENT);
            } else {
                while (__hip_atomic_load(release, __ATOMIC_RELAXED,
                                         __HIP_MEMORY_SCOPE_AGENT) < (unsigned)l)
                    __builtin_amdgcn_s_sleep(1);
            }
        }
        asm volatile("s_barrier" ::: "memory");    // intra-block release

        // ---- compute level l: fresh gathers (srcs in level l-1) + reduce ----
        if (active) {
            const int v   = l * PER + wid;
            const int lim = (l - 1) * PER;          // >= lim -> fresh
#pragma unroll
            for (int k = 0; k < DEG; ++k)
                if (sidx[k] >= lim)
                    g[k] = msg[(size_t)sidx[k] * DF + d];

            float m = -INFINITY;
#pragma unroll
            for (int k = 0; k < DEG; ++k) m = fmaxf(m, g[k]);

            const float o = m + dl;
            out[(size_t)v * DF + d] = o;
            if (l < LVL - 1)
                msg_store(&msg[(size_t)v * DF + d], o + it);
        }

        // ---- prefetch level l+1; old-source gathers fly across the barrier ----
        if (active && (l + 1 < LVL)) {
            const int vn = (l + 1) * PER + wid;
            const int4* sp4 = (const int4*)(src + (size_t)(vn - PER) * DEG);
#pragma unroll
            for (int q = 0; q < 4; ++q) {
                const int4 t = sp4[q];
                sidx[q*4+0] = __builtin_amdgcn_readfirstlane(t.x);
                sidx[q*4+1] = __builtin_amdgcn_readfirstlane(t.y);
                sidx[q*4+2] = __builtin_amdgcn_readfirstlane(t.z);
                sidx[q*4+3] = __builtin_amdgcn_readfirstlane(t.w);
            }
            dl = delay[(size_t)vn * DF + d];
            it = intra[(size_t)vn * DF + d];
            // Ack the msg sc1 store (and metadata loads) BEFORE issuing the
            // old gathers, so only the gathers remain in flight at arrive.
            asm volatile("s_waitcnt vmcnt(0)" ::: "memory");
            const int limn = l * PER;               // < limn -> final & visible
#pragma unroll
            for (int k = 0; k < DEG; ++k) {
                if (sidx[k] < limn) g[k] = msg[(size_t)sidx[k] * DF + d];
                else                g[k] = -INFINITY;
            }
        } else {
            asm volatile("s_waitcnt vmcnt(0)" ::: "memory");  // ack msg store
        }
    }
}

// ---- fallback path (ws too small): round-1 multi-kernel approach ----
__global__ void __launch_bounds__(256) prop_level(
    float* __restrict__ feat, const float* __restrict__ intra,
    const float* __restrict__ delay, const int* __restrict__ src, int level_start)
{
    const int idx = blockIdx.x * 4 + (threadIdx.x >> 6);
    if (idx >= PER) return;
    const int v = level_start + idx;
    const int d = threadIdx.x & 63;
    const long ebase = (long)(v - PER) * DEG;
    float m = -INFINITY;
#pragma unroll
    for (int k = 0; k < DEG; ++k) {
        const int s = src[ebase + k];
        m = fmaxf(m, feat[(long)s * DF + d] + intra[(long)s * DF + d]);
    }
    feat[(long)v * DF + d] = m + delay[(long)v * DF + d];
}

extern "C" void kernel_launch(void* const* d_in, const int* in_sizes, int n_in,
                              void* d_out, int out_size, void* d_ws, size_t ws_size,
                              hipStream_t stream) {
    const float* feat  = (const float*)d_in[0];
    const float* delay = (const float*)d_in[1];
    const float* intra = (const float*)d_in[2];
    const int*   src   = (const int*)d_in[3];
    float* out = (float*)d_out;

    const size_t need = 256 + (size_t)NN * DF * sizeof(float);
    if (ws_size >= need) {
        unsigned* counter = (unsigned*)d_ws;                  // line 0
        unsigned* release = (unsigned*)((char*)d_ws + 128);   // line 1
        float*    msg     = (float*)((char*)d_ws + 256);
        hipMemsetAsync(d_ws, 0, 256, stream);   // reset barrier state each call
        prop_all<<<NBLK, NTHR, 0, stream>>>(feat, delay, intra, src, out, msg,
                                            counter, release);
    } else {
        hipMemcpyAsync(out, feat, (size_t)NN * DF * sizeof(float),
                       hipMemcpyDeviceToDevice, stream);
        const int blocks = (PER + 3) / 4;
        for (int l = 1; l < LVL; ++l)
            prop_level<<<blocks, 256, 0, stream>>>(out, intra, delay, src, l * PER);
    }
}

// Round 6
// 87.332 us; speedup vs baseline: 3.3673x; 1.0306x over previous
//
#include <hip/hip_runtime.h>
#include <hip/hip_bf16.h>

// GraphProp: layered DAG topological propagation.
// N=50000, L=16 levels, PER=3125/level, DEG=16 in-edges, D=64 feat dim.
// Edges sorted by dst; node v (v>=PER) owns edges [(v-PER)*16, (v-PER)*16+16).
// feat[v] = max_k(feat[src_k] + intra_delay[src_k]) + delay[v], level order.
//
// R6: NO grid barriers -- per-node dataflow with ready flags.
//   - One wave per node per level (wave wid owns node l*PER+wid for all l).
//   - Producer: msg row via agent-scope relaxed (sc1, write-through to LLC)
//     stores, vmcnt(0) drain (row durable at LLC), then flags[v]=1 (sc1).
//   - Consumer: polls its 16 source flags with agent-scope relaxed loads
//     (bypass L2 -- cached polls would spin on a stale 0); 64 lanes cover
//     the 16 flags 4x, one __all per probe.
//   - msg GATHERS are normal cached loads: a msg line is written (sc1,
//     bypassing L2) before any reader touches it, and kernel-start acquire
//     invalidates L2, so no L2 can ever hold a pre-final copy. LLC
//     serializes msg-ack before the flag store, so flag=1 => row readable.
//   - Next-level metadata (src row, delay, intra, poll idx) issued BEFORE
//     the poll loop; latency hides under the spin.
//   - flags[] must start 0 each call (ws is poisoned 0xAA once): one small
//     hipMemsetAsync(200KB) ahead of the kernel.
// Rationale: R5 showed ~5.7us/level of pure grid-barrier latency (R3==R4
// proved gathers aren't the cost). Dataflow replaces 15 full-grid round
// trips with per-node flag hops; stragglers overlap instead of stalling
// all 4096 waves.

#define NN    50000
#define LVL   16
#define PER   3125
#define DEG   16
#define DF    64

#define NBLK  256
#define NTHR  1024

#define RFL __builtin_amdgcn_readfirstlane

__device__ __forceinline__ void st_agent_f(float* p, float v) {
    __hip_atomic_store(p, v, __ATOMIC_RELAXED, __HIP_MEMORY_SCOPE_AGENT);
}
__device__ __forceinline__ void st_agent_u(unsigned* p, unsigned v) {
    __hip_atomic_store(p, v, __ATOMIC_RELAXED, __HIP_MEMORY_SCOPE_AGENT);
}
__device__ __forceinline__ unsigned ld_agent_u(const unsigned* p) {
    return __hip_atomic_load(p, __ATOMIC_RELAXED, __HIP_MEMORY_SCOPE_AGENT);
}

__global__ void __launch_bounds__(NTHR) prop_dataflow(
    const float* __restrict__ feat,
    const float* __restrict__ delay,
    const float* __restrict__ intra,
    const int*  __restrict__ src,
    float* __restrict__ out,
    float* __restrict__ msg,
    unsigned* __restrict__ flags)
{
    const int tid  = blockIdx.x * NTHR + threadIdx.x;
    const int wid  = tid >> 6;              // global wave id = node-within-level
    const int lane = threadIdx.x & 63;
    if (wid >= PER) return;                 // 3125 working waves; rest exit

    // ---- level-0 init: wave w owns exactly row w (PER*DF == 64*PER) ----
    {
        const float f = feat[tid];          // tid == wid*64 + lane
        out[tid] = f;
        st_agent_f(&msg[tid], f + intra[tid]);
        asm volatile("s_waitcnt vmcnt(0)" ::: "memory");   // row at LLC
        if (lane == 0) st_agent_u(&flags[wid], 1u);
    }

    const int d = lane;

    // ---- metadata for level 1 ----
    int4 t0, t1, t2, t3; float dl, it; int msrc;
    {
        const int vn = PER + wid;
        const size_t eb = (size_t)(vn - PER) * DEG;
        const int4* sp4 = (const int4*)(src + eb);
        t0 = sp4[0]; t1 = sp4[1]; t2 = sp4[2]; t3 = sp4[3];
        dl = delay[(size_t)vn * DF + d];
        it = intra[(size_t)vn * DF + d];
        msrc = src[eb + (lane & 15)];       // per-lane poll index (4x dup)
    }
    int sidx[16];                            // wave-uniform scalar copies
    sidx[0]=RFL(t0.x); sidx[1]=RFL(t0.y); sidx[2]=RFL(t0.z); sidx[3]=RFL(t0.w);
    sidx[4]=RFL(t1.x); sidx[5]=RFL(t1.y); sidx[6]=RFL(t1.z); sidx[7]=RFL(t1.w);
    sidx[8]=RFL(t2.x); sidx[9]=RFL(t2.y); sidx[10]=RFL(t2.z); sidx[11]=RFL(t2.w);
    sidx[12]=RFL(t3.x); sidx[13]=RFL(t3.y); sidx[14]=RFL(t3.z); sidx[15]=RFL(t3.w);

#pragma unroll 1
    for (int l = 1; l < LVL; ++l) {
        const int v = l * PER + wid;

        // Issue next-level metadata loads early (flag-independent);
        // their latency hides under the poll loop.
        int4 n0 = t0, n1 = t1, n2 = t2, n3 = t3;
        float dln = dl, itn = it; int msrcn = msrc;
        if (l + 1 < LVL) {
            const int vq = v + PER;
            const size_t eb = (size_t)(vq - PER) * DEG;
            const int4* np4 = (const int4*)(src + eb);
            n0 = np4[0]; n1 = np4[1]; n2 = np4[2]; n3 = np4[3];
            dln = delay[(size_t)vq * DF + d];
            itn = intra[(size_t)vq * DF + d];
            msrcn = src[eb + (lane & 15)];
        }
        asm volatile("" ::: "memory");      // pin meta issue above the poll

        // ---- wait for all 16 sources ----
        while (!__all(ld_agent_u(&flags[msrc]) != 0u))
            __builtin_amdgcn_s_sleep(1);
        asm volatile("" ::: "memory");      // no gather hoisting above poll

        // ---- gather (cached) + reduce ----
        float m = -INFINITY;
#pragma unroll
        for (int k = 0; k < DEG; ++k)
            m = fmaxf(m, msg[(size_t)(sidx[k] * DF) + d]);

        const float o = m + dl;
        out[(size_t)v * DF + d] = o;        // cached, kernel-end flush
        if (l < LVL - 1) {
            st_agent_f(&msg[(size_t)v * DF + d], o + it);
            asm volatile("s_waitcnt vmcnt(0)" ::: "memory");  // row at LLC
            if (lane == 0) st_agent_u(&flags[v], 1u);
        }

        // rotate metadata for next level
        sidx[0]=RFL(n0.x); sidx[1]=RFL(n0.y); sidx[2]=RFL(n0.z); sidx[3]=RFL(n0.w);
        sidx[4]=RFL(n1.x); sidx[5]=RFL(n1.y); sidx[6]=RFL(n1.z); sidx[7]=RFL(n1.w);
        sidx[8]=RFL(n2.x); sidx[9]=RFL(n2.y); sidx[10]=RFL(n2.z); sidx[11]=RFL(n2.w);
        sidx[12]=RFL(n3.x); sidx[13]=RFL(n3.y); sidx[14]=RFL(n3.z); sidx[15]=RFL(n3.w);
        dl = dln; it = itn; msrc = msrcn;
    }
}

// ---- fallback path (ws too small): round-1 multi-kernel approach ----
__global__ void __launch_bounds__(256) prop_level(
    float* __restrict__ feat, const float* __restrict__ intra,
    const float* __restrict__ delay, const int* __restrict__ src, int level_start)
{
    const int idx = blockIdx.x * 4 + (threadIdx.x >> 6);
    if (idx >= PER) return;
    const int v = level_start + idx;
    const int d = threadIdx.x & 63;
    const long ebase = (long)(v - PER) * DEG;
    float m = -INFINITY;
#pragma unroll
    for (int k = 0; k < DEG; ++k) {
        const int s = src[ebase + k];
        m = fmaxf(m, feat[(long)s * DF + d] + intra[(long)s * DF + d]);
    }
    feat[(long)v * DF + d] = m + delay[(long)v * DF + d];
}

extern "C" void kernel_launch(void* const* d_in, const int* in_sizes, int n_in,
                              void* d_out, int out_size, void* d_ws, size_t ws_size,
                              hipStream_t stream) {
    const float* feat  = (const float*)d_in[0];
    const float* delay = (const float*)d_in[1];
    const float* intra = (const float*)d_in[2];
    const int*   src   = (const int*)d_in[3];
    float* out = (float*)d_out;

    const size_t flags_bytes = (size_t)NN * sizeof(unsigned);   // 200 KB
    const size_t msg_off     = 262144;                          // 256 KB align
    const size_t need        = msg_off + (size_t)NN * DF * sizeof(float);

    if (ws_size >= need) {
        unsigned* flags = (unsigned*)d_ws;
        float*    msg   = (float*)((char*)d_ws + msg_off);
        hipMemsetAsync(d_ws, 0, flags_bytes, stream);   // flags must start 0
        prop_dataflow<<<NBLK, NTHR, 0, stream>>>(feat, delay, intra, src,
                                                 out, msg, flags);
    } else {
        hipMemcpyAsync(out, feat, (size_t)NN * DF * sizeof(float),
                       hipMemcpyDeviceToDevice, stream);
        const int blocks = (PER + 3) / 4;
        for (int l = 1; l < LVL; ++l)
            prop_level<<<blocks, 256, 0, stream>>>(out, intra, delay, src, l * PER);
    }
}